// Round 1
// baseline (925.544 us; speedup 1.0000x reference)
//
#include <hip/hip_runtime.h>
#include <stdint.h>

// SNN: conv(2->8,3x3,SAME on 512x32) -> LIF(T=4) -> FC 131072->512 -> LIF
//      -> FC 512->512 -> LIF -> mean over T -> FC 512->16
// All fp32 I/O. tau=2: v = 0.5*v + x; spike v>=1; hard reset to 0.
//
// Output layout (concat, fp32):
//   out:        (128,16)            @ 0
//   conv_spk:   (128,4,8,512,32)    @ 2048
//   input_spk:  (128,4,512)         @ 67110912
//   hidden_spk: (128,4,512)         @ 67373056

#define OFF_CONV  2048ll
#define OFF_IN    67110912ll
#define OFF_HID   67373056ll

typedef short bf16x8 __attribute__((ext_vector_type(8)));
typedef float f32x4  __attribute__((ext_vector_type(4)));

__device__ __forceinline__ unsigned short f2bf(float f) {
  unsigned u = __float_as_uint(f);
  u += 0x7FFFu + ((u >> 16) & 1u);   // round-to-nearest-even to bf16
  return (unsigned short)(u >> 16);
}

// ---------------------------------------------------------------------------
// Kernel 1: conv + LIF over T=4. One thread per (b, co, h, w).
// Writes fp32 spikes to d_out (conv_spk_rec) and a 4-bit pattern byte to ws.
// ---------------------------------------------------------------------------
__global__ __launch_bounds__(256) void conv_lif_kernel(
    const float* __restrict__ x, const float* __restrict__ wc,
    float* __restrict__ out, unsigned char* __restrict__ patt)
{
  __shared__ float wcs[144];
  int tid = threadIdx.x;
  if (tid < 144) wcs[tid] = wc[tid];
  __syncthreads();

  long long idx = (long long)blockIdx.x * 256 + tid;  // b*131072 + k
  int b   = (int)(idx >> 17);
  int k   = (int)(idx & 131071);
  int co  = k >> 14;
  int rem = k & 16383;
  int h   = rem >> 5;
  int w   = rem & 31;

  const float* xb = x + (long long)b * 32768;  // (2, 512, 32) per batch
  float c = 0.f;
#pragma unroll
  for (int ci = 0; ci < 2; ++ci) {
    const float* xc = xb + ci * 16384;
    const float* wk = wcs + co * 18 + ci * 9;
#pragma unroll
    for (int dh = -1; dh <= 1; ++dh) {
      int hh = h + dh;
      if (hh < 0 || hh >= 512) continue;
#pragma unroll
      for (int dw = -1; dw <= 1; ++dw) {
        int ww = w + dw;
        if (ww < 0 || ww >= 32) continue;
        c += xc[hh * 32 + ww] * wk[(dh + 1) * 3 + (dw + 1)];
      }
    }
  }

  // LIF, exactly mirroring reference fp32 semantics
  float v = 0.f;
  unsigned p = 0;
  float* ob = out + OFF_CONV + (long long)b * 524288 + k;
#pragma unroll
  for (int t = 0; t < 4; ++t) {
    v = v * 0.5f + c;
    int si = (v >= 1.0f) ? 1 : 0;
    ob[t * 131072] = (float)si;
    if (si) v = 0.f;
    p |= (unsigned)si << t;
  }
  patt[(long long)b * 131072 + k] = (unsigned char)p;
}

// ---------------------------------------------------------------------------
// Kernel 2: transpose w2 (512x512) -> w2t for coalesced FC2 reads
// ---------------------------------------------------------------------------
__global__ __launch_bounds__(256) void transpose512(
    const float* __restrict__ w2, float* __restrict__ w2t)
{
  __shared__ float tile[32][33];
  int bx = blockIdx.x & 15, by = blockIdx.x >> 4;
  int tx = threadIdx.x & 31, ty = threadIdx.x >> 5;  // 32 x 8
#pragma unroll
  for (int i = 0; i < 32; i += 8)
    tile[ty + i][tx] = w2[(by * 32 + ty + i) * 512 + bx * 32 + tx];
  __syncthreads();
#pragma unroll
  for (int i = 0; i < 32; i += 8)
    w2t[(bx * 32 + ty + i) * 512 + by * 32 + tx] = tile[tx][ty + i];
}

// ---------------------------------------------------------------------------
// Kernel 3: big GEMM  Z1[m=t*128+b][n] = sum_k spike[t][b][k] * w1[n][k]
// A expanded from pattern bits (bf16 {0,1}), B = w1 split hi/lo bf16 on the
// fly, both MFMA'd into one fp32 acc. 128x128 tile, BK=32, split-K.
// ---------------------------------------------------------------------------
__global__ __launch_bounds__(256, 2) void gemm_kernel(
    const unsigned char* __restrict__ patt, const float* __restrict__ w1,
    float* __restrict__ partials, int steps)
{
  __shared__ unsigned short As[128][40];   // +8 pad: bank-friendly, 16B-aligned rows
  __shared__ unsigned short Bh[128][40];
  __shared__ unsigned short Bl[128][40];

  const int tid   = threadIdx.x;
  const int tile  = blockIdx.x & 15;
  const int chunk = blockIdx.x >> 4;
  const int nt = tile >> 2;
  const int mt = tile & 3;                 // == timestep t of this M-tile
  const long long k0 = (long long)chunk * steps * 32;

  const int r  = tid & 127;                // staging row
  const int kh = tid >> 7;                 // staging k-half (16 elems)

  const unsigned char* pA = patt + (long long)r * 131072 + k0 + kh * 16;
  const float* pB = w1 + (long long)(nt * 128 + r) * 131072 + k0 + kh * 16;

  const int lane = tid & 63;
  const int wid  = tid >> 6;
  const int wm = wid >> 1, wn = wid & 1;   // 2x2 waves -> 64x64 each
  const int l15 = lane & 15, quad = lane >> 4;

  f32x4 acc[4][4];
#pragma unroll
  for (int i = 0; i < 4; ++i)
#pragma unroll
    for (int j = 0; j < 4; ++j) acc[i][j] = (f32x4){0.f, 0.f, 0.f, 0.f};

  for (int s = 0; s < steps; ++s) {
    uint4  pa = *(const uint4*)(pA + s * 32);
    float4 f0 = *(const float4*)(pB + s * 32 + 0);
    float4 f1 = *(const float4*)(pB + s * 32 + 4);
    float4 f2 = *(const float4*)(pB + s * 32 + 8);
    float4 f3 = *(const float4*)(pB + s * 32 + 12);

    __syncthreads();  // previous iteration's LDS reads complete

    // --- A: expand bit `mt` of 16 pattern bytes -> 16 bf16 {0,1} ---
    unsigned dw[4] = {pa.x, pa.y, pa.z, pa.w};
    unsigned ap[8];
#pragma unroll
    for (int d = 0; d < 4; ++d) {
      unsigned b0 = (dw[d] >> mt) & 1u;
      unsigned b1 = (dw[d] >> (8 + mt)) & 1u;
      unsigned b2 = (dw[d] >> (16 + mt)) & 1u;
      unsigned b3 = (dw[d] >> (24 + mt)) & 1u;
      ap[d * 2 + 0] = b0 * 0x3F80u | b1 * 0x3F800000u;
      ap[d * 2 + 1] = b2 * 0x3F80u | b3 * 0x3F800000u;
    }
    *(uint4*)&As[r][kh * 16 + 0] = make_uint4(ap[0], ap[1], ap[2], ap[3]);
    *(uint4*)&As[r][kh * 16 + 8] = make_uint4(ap[4], ap[5], ap[6], ap[7]);

    // --- B: fp32 -> (hi, lo) bf16 pair ---
    float fv[16] = {f0.x, f0.y, f0.z, f0.w, f1.x, f1.y, f1.z, f1.w,
                    f2.x, f2.y, f2.z, f2.w, f3.x, f3.y, f3.z, f3.w};
    unsigned hp[8], lp[8];
#pragma unroll
    for (int i = 0; i < 8; ++i) {
      unsigned short h0 = f2bf(fv[2 * i]);
      unsigned short h1 = f2bf(fv[2 * i + 1]);
      float r0 = fv[2 * i]     - __uint_as_float((unsigned)h0 << 16);
      float r1 = fv[2 * i + 1] - __uint_as_float((unsigned)h1 << 16);
      unsigned short l0 = f2bf(r0);
      unsigned short l1 = f2bf(r1);
      hp[i] = (unsigned)h0 | ((unsigned)h1 << 16);
      lp[i] = (unsigned)l0 | ((unsigned)l1 << 16);
    }
    *(uint4*)&Bh[r][kh * 16 + 0] = make_uint4(hp[0], hp[1], hp[2], hp[3]);
    *(uint4*)&Bh[r][kh * 16 + 8] = make_uint4(hp[4], hp[5], hp[6], hp[7]);
    *(uint4*)&Bl[r][kh * 16 + 0] = make_uint4(lp[0], lp[1], lp[2], lp[3]);
    *(uint4*)&Bl[r][kh * 16 + 8] = make_uint4(lp[4], lp[5], lp[6], lp[7]);

    __syncthreads();

    bf16x8 a[4], bh[4], bl[4];
#pragma unroll
    for (int f = 0; f < 4; ++f)
      a[f] = *(const bf16x8*)&As[wm * 64 + f * 16 + l15][quad * 8];
#pragma unroll
    for (int f = 0; f < 4; ++f) {
      bh[f] = *(const bf16x8*)&Bh[wn * 64 + f * 16 + l15][quad * 8];
      bl[f] = *(const bf16x8*)&Bl[wn * 64 + f * 16 + l15][quad * 8];
    }
#pragma unroll
    for (int fm = 0; fm < 4; ++fm)
#pragma unroll
      for (int fn = 0; fn < 4; ++fn) {
        acc[fm][fn] = __builtin_amdgcn_mfma_f32_16x16x32_bf16(a[fm], bh[fn], acc[fm][fn], 0, 0, 0);
        acc[fm][fn] = __builtin_amdgcn_mfma_f32_16x16x32_bf16(a[fm], bl[fn], acc[fm][fn], 0, 0, 0);
      }
  }

  // epilogue: partials[chunk][m][n]; D: row = quad*4+reg (M), col = l15 (N)
  float* pc = partials + (long long)chunk * 262144;
#pragma unroll
  for (int fm = 0; fm < 4; ++fm)
#pragma unroll
    for (int fn = 0; fn < 4; ++fn) {
      int m0 = mt * 128 + wm * 64 + fm * 16 + quad * 4;
      int n  = nt * 128 + wn * 64 + fn * 16 + l15;
#pragma unroll
      for (int rg = 0; rg < 4; ++rg)
        pc[(long long)(m0 + rg) * 512 + n] = acc[fm][fn][rg];
    }
}

// ---------------------------------------------------------------------------
// Kernel 4: split-K reduce (deterministic ascending-chunk order)
// ---------------------------------------------------------------------------
__global__ __launch_bounds__(256) void reduce_kernel(
    const float* __restrict__ partials, float* __restrict__ z1, int S)
{
  int idx = blockIdx.x * 256 + threadIdx.x;  // 0..262143
  float a = 0.f;
  for (int c = 0; c < S; ++c) a += partials[(long long)c * 262144 + idx];
  z1[idx] = a;
}

// ---------------------------------------------------------------------------
// Kernel 5: per-batch FC pipeline: LIF1 -> FC2 -> LIF2 -> mean -> readout.
// One block per b (512 threads = one neuron each).
// ---------------------------------------------------------------------------
__global__ __launch_bounds__(512) void fc_kernel(
    const float* __restrict__ z1, const float* __restrict__ w2t,
    const float* __restrict__ wout, float* __restrict__ out)
{
  int b = blockIdx.x;
  int n = threadIdx.x;
  __shared__ float s1s[512];
  __shared__ float red[512];

  float v1 = 0.f, v2 = 0.f, ssum = 0.f;
#pragma unroll
  for (int t = 0; t < 4; ++t) {
    float z = z1[((t * 128 + b) << 9) + n];
    v1 = v1 * 0.5f + z;
    float s1 = (v1 >= 1.0f) ? 1.f : 0.f;
    out[OFF_IN + ((long long)b * 4 + t) * 512 + n] = s1;
    if (s1 != 0.f) v1 = 0.f;
    s1s[n] = s1;
    __syncthreads();

    float z2 = 0.f;
    for (int k = 0; k < 512; ++k) {
      float sk = s1s[k];                 // uniform across block
      if (sk != 0.f) z2 += w2t[(k << 9) + n];
    }
    v2 = v2 * 0.5f + z2;
    float s2 = (v2 >= 1.0f) ? 1.f : 0.f;
    out[OFF_HID + ((long long)b * 4 + t) * 512 + n] = s2;
    if (s2 != 0.f) v2 = 0.f;
    ssum += s2;
    __syncthreads();                     // before s1s overwrite next t
  }

  s1s[n] = ssum * 0.25f;                 // mean spikes, reuse LDS
  __syncthreads();

  int o = n & 15, part = n >> 4;         // 16 outputs x 32 partials
  float p = 0.f;
#pragma unroll
  for (int j = 0; j < 16; ++j)
    p += s1s[part * 16 + j] * wout[o * 512 + part * 16 + j];
  red[n] = p;
  __syncthreads();
  if (n < 16) {
    float a = 0.f;
#pragma unroll
    for (int pp = 0; pp < 32; ++pp) a += red[pp * 16 + n];
    out[b * 16 + n] = a;
  }
}

// ---------------------------------------------------------------------------
extern "C" void kernel_launch(void* const* d_in, const int* in_sizes, int n_in,
                              void* d_out, int out_size, void* d_ws, size_t ws_size,
                              hipStream_t stream) {
  const float* x     = (const float*)d_in[0];
  const float* wconv = (const float*)d_in[1];
  const float* w1    = (const float*)d_in[2];
  const float* w2    = (const float*)d_in[3];
  const float* wout  = (const float*)d_in[4];
  float* out = (float*)d_out;
  char* ws = (char*)d_ws;

  unsigned char* patt = (unsigned char*)ws;                 // 16 MB
  float* w2t      = (float*)(ws + 16777216);                // 1 MB
  float* z1       = (float*)(ws + 16777216 + 1048576);      // 1 MB
  float* partials = (float*)(ws + 16777216 + 2097152);      // S MB

  int S = 32;
  while (S > 1 && (size_t)(18874368ull + (size_t)S * 1048576ull) > ws_size) S >>= 1;
  int steps = 4096 / S;  // K-steps of 32 per chunk

  hipLaunchKernelGGL(conv_lif_kernel, dim3(65536), dim3(256), 0, stream,
                     x, wconv, out, patt);
  hipLaunchKernelGGL(transpose512, dim3(256), dim3(256), 0, stream, w2, w2t);
  hipLaunchKernelGGL(gemm_kernel, dim3(16 * S), dim3(256), 0, stream,
                     patt, w1, partials, steps);
  hipLaunchKernelGGL(reduce_kernel, dim3(1024), dim3(256), 0, stream,
                     partials, z1, S);
  hipLaunchKernelGGL(fc_kernel, dim3(128), dim3(512), 0, stream,
                     z1, w2t, wout, out);
}

// Round 2
// 682.686 us; speedup vs baseline: 1.3557x; 1.3557x over previous
//
#include <hip/hip_runtime.h>
#include <stdint.h>

// SNN: conv(2->8,3x3,SAME on 512x32) -> LIF(T=4) -> FC 131072->512 -> LIF
//      -> FC 512->512 -> LIF -> mean over T -> FC 512->16
// All fp32 I/O. tau=2: v = 0.5*v + x; spike v>=1; hard reset to 0.
//
// Output layout (concat, fp32):
//   out:        (128,16)            @ 0
//   conv_spk:   (128,4,8,512,32)    @ 2048
//   input_spk:  (128,4,512)         @ 67110912
//   hidden_spk: (128,4,512)         @ 67373056

#define OFF_CONV  2048ll
#define OFF_IN    67110912ll
#define OFF_HID   67373056ll

typedef short bf16x8 __attribute__((ext_vector_type(8)));
typedef float f32x4  __attribute__((ext_vector_type(4)));

__device__ __forceinline__ unsigned short f2bf(float f) {
  unsigned u = __float_as_uint(f);
  u += 0x7FFFu + ((u >> 16) & 1u);   // round-to-nearest-even to bf16
  return (unsigned short)(u >> 16);
}

// expand 4 spike bits (byte lanes of x, bit t already shifted to bit0 of each
// byte) -> two dwords of packed bf16 {0,1}
__device__ __forceinline__ void expand2(unsigned x, unsigned& o0, unsigned& o1) {
  // x = b0 | b1<<8 | b2<<16 | b3<<24, each 0/1
  o0 = (x & 1u) * 0x3F80u | (x & 0x100u) * 0x3F8000u;
  unsigned y = x >> 16;
  o1 = (y & 1u) * 0x3F80u | (y & 0x100u) * 0x3F8000u;
}

// ---------------------------------------------------------------------------
// Kernel 1: conv + LIF over T=4. One thread per (b, co, h, w0..w0+3).
// Writes fp32 spikes to d_out (conv_spk_rec) and 4-bit pattern bytes to ws.
// ---------------------------------------------------------------------------
__global__ __launch_bounds__(256) void conv_lif_kernel(
    const float* __restrict__ x, const float* __restrict__ wc,
    float* __restrict__ out, unsigned char* __restrict__ patt)
{
  __shared__ float wcs[144];
  int tid = threadIdx.x;
  if (tid < 144) wcs[tid] = wc[tid];
  __syncthreads();

  int idx = blockIdx.x * 256 + tid;        // b*32768 + co*4096 + h*8 + wq
  int b   = idx >> 15;
  int k4  = idx & 32767;
  int co  = k4 >> 12;
  int rem = k4 & 4095;
  int h   = rem >> 3;
  int w0  = (rem & 7) * 4;

  const float* xb = x + (long long)b * 32768;  // (2, 512, 32) per batch
  float c[4] = {0.f, 0.f, 0.f, 0.f};
#pragma unroll
  for (int ci = 0; ci < 2; ++ci) {
    const float* xc = xb + ci * 16384;
    const float* wk = wcs + co * 18 + ci * 9;
    float win[3][6];
#pragma unroll
    for (int r = 0; r < 3; ++r) {
      int hh = h - 1 + r;
      if (hh >= 0 && hh < 512) {
        const float* row = xc + hh * 32;
        float4 m = *(const float4*)(row + w0);
        win[r][1] = m.x; win[r][2] = m.y; win[r][3] = m.z; win[r][4] = m.w;
        win[r][0] = (w0 > 0)  ? row[w0 - 1] : 0.f;
        win[r][5] = (w0 < 28) ? row[w0 + 4] : 0.f;
      } else {
#pragma unroll
        for (int j = 0; j < 6; ++j) win[r][j] = 0.f;
      }
    }
#pragma unroll
    for (int r = 0; r < 3; ++r)
#pragma unroll
      for (int dw = 0; dw < 3; ++dw) {
        float wgt = wk[r * 3 + dw];
#pragma unroll
        for (int j = 0; j < 4; ++j) c[j] += win[r][j + dw] * wgt;
      }
  }

  // LIF, exactly mirroring reference fp32 semantics
  int k = co * 16384 + h * 32 + w0;
  float* ob = out + OFF_CONV + (long long)b * 524288 + k;
  float v[4] = {0.f, 0.f, 0.f, 0.f};
  unsigned p[4] = {0, 0, 0, 0};
#pragma unroll
  for (int t = 0; t < 4; ++t) {
    float4 sv;
    float sj[4];
#pragma unroll
    for (int j = 0; j < 4; ++j) {
      v[j] = v[j] * 0.5f + c[j];
      int si = (v[j] >= 1.0f) ? 1 : 0;
      sj[j] = (float)si;
      if (si) v[j] = 0.f;
      p[j] |= (unsigned)si << t;
    }
    sv.x = sj[0]; sv.y = sj[1]; sv.z = sj[2]; sv.w = sj[3];
    *(float4*)(ob + t * 131072) = sv;
  }
  unsigned pb = p[0] | (p[1] << 8) | (p[2] << 16) | (p[3] << 24);
  *(unsigned*)(patt + (long long)b * 131072 + k) = pb;
}

// ---------------------------------------------------------------------------
// Kernel 2: transpose w2 (512x512) -> w2t for coalesced FC2 reads
// ---------------------------------------------------------------------------
__global__ __launch_bounds__(256) void transpose512(
    const float* __restrict__ w2, float* __restrict__ w2t)
{
  __shared__ float tile[32][33];
  int bx = blockIdx.x & 15, by = blockIdx.x >> 4;
  int tx = threadIdx.x & 31, ty = threadIdx.x >> 5;  // 32 x 8
#pragma unroll
  for (int i = 0; i < 32; i += 8)
    tile[ty + i][tx] = w2[(by * 32 + ty + i) * 512 + bx * 32 + tx];
  __syncthreads();
#pragma unroll
  for (int i = 0; i < 32; i += 8)
    w2t[(bx * 32 + ty + i) * 512 + by * 32 + tx] = tile[tx][ty + i];
}

// ---------------------------------------------------------------------------
// Kernel 3: big GEMM  Z1[m=t*128+b][n] = sum_k spike[t][b][k] * w1[n][k]
// One block handles ALL 4 timesteps (same pattern bytes, 4-bit expand) so w1
// is fetched once. 512 threads = 8 waves: wave (t, n-half) -> 128x64 subtile.
// B = w1 split hi/lo bf16 on the fly, both MFMA'd into one fp32 acc.
// ---------------------------------------------------------------------------
__global__ __launch_bounds__(512, 2) void gemm_kernel(
    const unsigned char* __restrict__ patt, const float* __restrict__ w1,
    float* __restrict__ partials, int steps)
{
  __shared__ unsigned short As[4][128][40];  // +8 pad rows (2-way bank alias = free)
  __shared__ unsigned short Bh[128][40];
  __shared__ unsigned short Bl[128][40];

  const int tid   = threadIdx.x;
  const int nt    = blockIdx.x & 3;          // N-tile (128 w1 rows)
  const int chunk = blockIdx.x >> 2;         // split-K chunk
  const long long k0 = (long long)chunk * steps * 32;

  const int r  = tid >> 2;                   // staging row 0..127
  const int ko = (tid & 3) * 8;              // staging k-offset (8 elems)

  const unsigned char* pA = patt + (long long)r * 131072 + k0 + ko;
  const float* pB = w1 + (long long)(nt * 128 + r) * 131072 + k0 + ko;

  const int lane = tid & 63;
  const int wid  = tid >> 6;                 // 0..7
  const int t    = wid >> 1;                 // timestep
  const int nh   = wid & 1;                  // n-half (64)
  const int l15 = lane & 15, quad = lane >> 4;

  f32x4 acc[8][4];
#pragma unroll
  for (int i = 0; i < 8; ++i)
#pragma unroll
    for (int j = 0; j < 4; ++j) acc[i][j] = (f32x4){0.f, 0.f, 0.f, 0.f};

  for (int s = 0; s < steps; ++s) {
    uint2  pa = *(const uint2*)(pA + s * 32);
    float4 f0 = *(const float4*)(pB + s * 32 + 0);
    float4 f1 = *(const float4*)(pB + s * 32 + 4);

    __syncthreads();  // previous iteration's LDS reads complete

    // --- A: expand bit tt of 8 pattern bytes -> 8 bf16 {0,1}, all 4 t ---
#pragma unroll
    for (int tt = 0; tt < 4; ++tt) {
      unsigned x0 = (pa.x >> tt) & 0x01010101u;
      unsigned x1 = (pa.y >> tt) & 0x01010101u;
      unsigned o0, o1, o2, o3;
      expand2(x0, o0, o1);
      expand2(x1, o2, o3);
      *(uint4*)&As[tt][r][ko] = make_uint4(o0, o1, o2, o3);
    }

    // --- B: fp32 -> (hi, lo) bf16 pair ---
    float fv[8] = {f0.x, f0.y, f0.z, f0.w, f1.x, f1.y, f1.z, f1.w};
    unsigned hp[4], lp[4];
#pragma unroll
    for (int i = 0; i < 4; ++i) {
      unsigned short h0 = f2bf(fv[2 * i]);
      unsigned short h1 = f2bf(fv[2 * i + 1]);
      float r0 = fv[2 * i]     - __uint_as_float((unsigned)h0 << 16);
      float r1 = fv[2 * i + 1] - __uint_as_float((unsigned)h1 << 16);
      hp[i] = (unsigned)h0 | ((unsigned)f2bf(r1), 0u) * 0u | ((unsigned)h1 << 16);
      lp[i] = (unsigned)f2bf(r0) | ((unsigned)f2bf(r1) << 16);
    }
    *(uint4*)&Bh[r][ko] = make_uint4(hp[0], hp[1], hp[2], hp[3]);
    *(uint4*)&Bl[r][ko] = make_uint4(lp[0], lp[1], lp[2], lp[3]);

    __syncthreads();

    bf16x8 a[8], bh[4], bl[4];
#pragma unroll
    for (int f = 0; f < 8; ++f)
      a[f] = *(const bf16x8*)&As[t][f * 16 + l15][quad * 8];
#pragma unroll
    for (int f = 0; f < 4; ++f) {
      bh[f] = *(const bf16x8*)&Bh[nh * 64 + f * 16 + l15][quad * 8];
      bl[f] = *(const bf16x8*)&Bl[nh * 64 + f * 16 + l15][quad * 8];
    }
#pragma unroll
    for (int fm = 0; fm < 8; ++fm)
#pragma unroll
      for (int fn = 0; fn < 4; ++fn) {
        acc[fm][fn] = __builtin_amdgcn_mfma_f32_16x16x32_bf16(a[fm], bh[fn], acc[fm][fn], 0, 0, 0);
        acc[fm][fn] = __builtin_amdgcn_mfma_f32_16x16x32_bf16(a[fm], bl[fn], acc[fm][fn], 0, 0, 0);
      }
  }

  // epilogue: partials[chunk][t*128+b][n]; D: row = quad*4+reg (b), col = l15
  float* pc = partials + (long long)chunk * 262144;
#pragma unroll
  for (int fm = 0; fm < 8; ++fm)
#pragma unroll
    for (int fn = 0; fn < 4; ++fn) {
      int m = t * 128 + fm * 16 + quad * 4;
      int n = nt * 128 + nh * 64 + fn * 16 + l15;
#pragma unroll
      for (int rg = 0; rg < 4; ++rg)
        pc[(long long)(m + rg) * 512 + n] = acc[fm][fn][rg];
    }
}

// ---------------------------------------------------------------------------
// Kernel 4: split-K reduce (deterministic ascending-chunk order)
// ---------------------------------------------------------------------------
__global__ __launch_bounds__(256) void reduce_kernel(
    const float* __restrict__ partials, float* __restrict__ z1, int S)
{
  int idx = blockIdx.x * 256 + threadIdx.x;  // 0..262143
  float a = 0.f;
  for (int c = 0; c < S; ++c) a += partials[(long long)c * 262144 + idx];
  z1[idx] = a;
}

// ---------------------------------------------------------------------------
// Kernel 5: per-batch FC pipeline: LIF1 -> FC2 -> LIF2 -> mean -> readout.
// One block per b (512 threads = one neuron each). Branchless FC2 inner loop
// (adding exact 0.0f terms is an fp32 identity -> bitwise same as skipping).
// ---------------------------------------------------------------------------
__global__ __launch_bounds__(512) void fc_kernel(
    const float* __restrict__ z1, const float* __restrict__ w2t,
    const float* __restrict__ wout, float* __restrict__ out)
{
  int b = blockIdx.x;
  int n = threadIdx.x;
  __shared__ float s1s[512];
  __shared__ float red[512];

  float v1 = 0.f, v2 = 0.f, ssum = 0.f;
#pragma unroll
  for (int t = 0; t < 4; ++t) {
    float z = z1[((t * 128 + b) << 9) + n];
    v1 = v1 * 0.5f + z;
    float s1 = (v1 >= 1.0f) ? 1.f : 0.f;
    out[OFF_IN + ((long long)b * 4 + t) * 512 + n] = s1;
    if (s1 != 0.f) v1 = 0.f;
    s1s[n] = s1;
    __syncthreads();

    float z2 = 0.f;
#pragma unroll 8
    for (int k = 0; k < 512; ++k)
      z2 += s1s[k] * w2t[(k << 9) + n];
    v2 = v2 * 0.5f + z2;
    float s2 = (v2 >= 1.0f) ? 1.f : 0.f;
    out[OFF_HID + ((long long)b * 4 + t) * 512 + n] = s2;
    if (s2 != 0.f) v2 = 0.f;
    ssum += s2;
    __syncthreads();                     // before s1s overwrite next t
  }

  s1s[n] = ssum * 0.25f;                 // mean spikes, reuse LDS
  __syncthreads();

  int o = n & 15, part = n >> 4;         // 16 outputs x 32 partials
  float p = 0.f;
#pragma unroll
  for (int j = 0; j < 16; ++j)
    p += s1s[part * 16 + j] * wout[o * 512 + part * 16 + j];
  red[n] = p;
  __syncthreads();
  if (n < 16) {
    float a = 0.f;
#pragma unroll
    for (int pp = 0; pp < 32; ++pp) a += red[pp * 16 + n];
    out[b * 16 + n] = a;
  }
}

// ---------------------------------------------------------------------------
extern "C" void kernel_launch(void* const* d_in, const int* in_sizes, int n_in,
                              void* d_out, int out_size, void* d_ws, size_t ws_size,
                              hipStream_t stream) {
  const float* x     = (const float*)d_in[0];
  const float* wconv = (const float*)d_in[1];
  const float* w1    = (const float*)d_in[2];
  const float* w2    = (const float*)d_in[3];
  const float* wout  = (const float*)d_in[4];
  float* out = (float*)d_out;
  char* ws = (char*)d_ws;

  unsigned char* patt = (unsigned char*)ws;                 // 16 MB
  float* w2t      = (float*)(ws + 16777216);                // 1 MB
  float* z1       = (float*)(ws + 16777216 + 1048576);      // 1 MB
  float* partials = (float*)(ws + 16777216 + 2097152);      // S MB

  int S = 64;
  while (S > 1 && (size_t)(18874368ull + (size_t)S * 1048576ull) > ws_size) S >>= 1;
  int steps = 4096 / S;  // K-steps of 32 per chunk

  hipLaunchKernelGGL(conv_lif_kernel, dim3(16384), dim3(256), 0, stream,
                     x, wconv, out, patt);
  hipLaunchKernelGGL(transpose512, dim3(256), dim3(256), 0, stream, w2, w2t);
  hipLaunchKernelGGL(gemm_kernel, dim3(4 * S), dim3(512), 0, stream,
                     patt, w1, partials, steps);
  hipLaunchKernelGGL(reduce_kernel, dim3(1024), dim3(256), 0, stream,
                     partials, z1, S);
  hipLaunchKernelGGL(fc_kernel, dim3(128), dim3(512), 0, stream,
                     z1, w2t, wout, out);
}